// Round 2
// baseline (94.433 us; speedup 1.0000x reference)
//
#include <hip/hip_runtime.h>

#define BATCH 4096
#define DIM   128
#define NT    32   // 4096 / 128 tiles per dimension
// TEMP = 0.25 -> 1/T = 4; 4*log2(e):
#define EXP_SCALE 5.770780163555854f

typedef __bf16 bf16_t;
typedef __bf16 bf16x8 __attribute__((ext_vector_type(8)));
typedef float  f32x4  __attribute__((ext_vector_type(4)));

// ---------------------------------------------------------------------------
// Kernel A: per row k, normalize emb_i[k] and emb_j[k] (fp32 math), write
// bf16 z_i, z_j, pos[k] = cos-sim in fp32. One wave per row, 1024 blocks.
// Block 0 zeroes out[0] (accumulated by kernel C via atomicAdd).
// No denominator pre-zeroing needed anymore: kernel B writes deterministic
// partial arrays instead of atomics.
// ---------------------------------------------------------------------------
__global__ __launch_bounds__(256) void normalize_kernel(
    const float* __restrict__ emb_i, const float* __restrict__ emb_j,
    bf16_t* __restrict__ zi, bf16_t* __restrict__ zj, float* __restrict__ pos,
    float* __restrict__ out)
{
    if (blockIdx.x == 0 && threadIdx.x == 0) out[0] = 0.0f;

    const int wave = threadIdx.x >> 6;
    const int lane = threadIdx.x & 63;
    const int k = blockIdx.x * 4 + wave;

    const float2* ei = (const float2*)(emb_i + (size_t)k * DIM);
    const float2* ej = (const float2*)(emb_j + (size_t)k * DIM);
    float2 a = ei[lane];
    float2 b = ej[lane];

    float sii = a.x * a.x + a.y * a.y;
    float sjj = b.x * b.x + b.y * b.y;
    float sij = a.x * b.x + a.y * b.y;
#pragma unroll
    for (int m = 1; m < 64; m <<= 1) {
        sii += __shfl_xor(sii, m);
        sjj += __shfl_xor(sjj, m);
        sij += __shfl_xor(sij, m);
    }
    const float inv_i = 1.0f / fmaxf(sqrtf(sii), 1e-12f);
    const float inv_j = 1.0f / fmaxf(sqrtf(sjj), 1e-12f);

    struct bf16_2 { bf16_t x, y; };
    bf16_2 pi, pj;
    pi.x = (bf16_t)(a.x * inv_i);  pi.y = (bf16_t)(a.y * inv_i);
    pj.x = (bf16_t)(b.x * inv_j);  pj.y = (bf16_t)(b.y * inv_j);
    ((bf16_2*)(zi + (size_t)k * DIM))[lane] = pi;
    ((bf16_2*)(zj + (size_t)k * DIM))[lane] = pj;

    if (lane == 0) pos[k] = sij * inv_i * inv_j;
}

// ---------------------------------------------------------------------------
// Kernel B: 128x128 tile of S = Zi * Zj^T per block (grid 32x32), 256 thr.
// 4 waves in a 2x2 grid, each wave a 64x64 sub-tile: acc[4][4] f32x4 =
// 64 VGPRs (low pressure; round-0's fused 256^2 version needed 128 acc
// VGPRs at 512 threads -> suspected spill). LDS rows padded 128->136
// (row stride 272 B -> uniform free 2-way bank pattern on b128 access).
// 73.6 KB LDS -> 2 blocks/CU (stage/compute overlap across blocks).
// Epilogue: e = exp2(EXP_SCALE*s); row/col partial sums go to
// deterministic arrays rowP[tj][4096], colP[ti][4096] -- NO atomics.
// ---------------------------------------------------------------------------
__global__ __launch_bounds__(256, 2) void gemm_exp_kernel(
    const bf16_t* __restrict__ zi, const bf16_t* __restrict__ zj,
    float* __restrict__ rowP,   // [NT][BATCH], indexed [tj][global row]
    float* __restrict__ colP)   // [NT][BATCH], indexed [ti][global col]
{
    __shared__ __align__(16) bf16_t zi_s[128][136];
    __shared__ __align__(16) bf16_t zj_s[128][136];
    __shared__ float rowRed[2][128];
    __shared__ float colRed[2][128];

    const int tid = threadIdx.x;
    const int ti = blockIdx.x, tj = blockIdx.y;

    // Stage 128x128 bf16 of each matrix: 2048 16B-chunks / matrix, 8 iters.
#pragma unroll
    for (int it = 0; it < 8; ++it) {
        int c = it * 256 + tid;
        int row = c >> 4;          // 16 chunks per row
        int col = (c & 15) << 3;   // 8 bf16 per chunk
        *(uint4*)&zi_s[row][col] =
            *(const uint4*)(zi + ((size_t)(ti * 128 + row)) * DIM + col);
        *(uint4*)&zj_s[row][col] =
            *(const uint4*)(zj + ((size_t)(tj * 128 + row)) * DIM + col);
    }
    __syncthreads();

    const int wave = tid >> 6;
    const int lane = tid & 63;
    const int l15  = lane & 15;
    const int quad = lane >> 4;
    const int wr   = wave >> 1;   // 0..1 : row half (64 rows)
    const int wc   = wave & 1;    // 0..1 : col half (64 cols)

    f32x4 acc[4][4];
#pragma unroll
    for (int mr = 0; mr < 4; ++mr)
#pragma unroll
        for (int nc = 0; nc < 4; ++nc)
            acc[mr][nc] = (f32x4){0.f, 0.f, 0.f, 0.f};

#pragma unroll
    for (int ks = 0; ks < 4; ++ks) {
        const int k0 = ks * 32 + quad * 8;
        bf16x8 afrag[4], bfrag[4];
#pragma unroll
        for (int mr = 0; mr < 4; ++mr)
            afrag[mr] = *(const bf16x8*)&zi_s[wr * 64 + mr * 16 + l15][k0];
#pragma unroll
        for (int nc = 0; nc < 4; ++nc)
            bfrag[nc] = *(const bf16x8*)&zj_s[wc * 64 + nc * 16 + l15][k0];
#pragma unroll
        for (int mr = 0; mr < 4; ++mr)
#pragma unroll
            for (int nc = 0; nc < 4; ++nc)
                acc[mr][nc] = __builtin_amdgcn_mfma_f32_16x16x32_bf16(
                    afrag[mr], bfrag[nc], acc[mr][nc], 0, 0, 0);
    }

    // ---- Epilogue: exp + partial sums ----
    // C/D layout: col = l15, row = quad*4 + rr (within each 16x16 frag).
    float rowPart[4][4];
    float colPart[4] = {0.f, 0.f, 0.f, 0.f};
#pragma unroll
    for (int mr = 0; mr < 4; ++mr)
#pragma unroll
        for (int rr = 0; rr < 4; ++rr) rowPart[mr][rr] = 0.f;

#pragma unroll
    for (int mr = 0; mr < 4; ++mr)
#pragma unroll
        for (int nc = 0; nc < 4; ++nc)
#pragma unroll
            for (int rr = 0; rr < 4; ++rr) {
                const float e = exp2f(acc[mr][nc][rr] * EXP_SCALE);
                rowPart[mr][rr] += e;
                colPart[nc]     += e;
            }

    // Row sums: reduce over the 16 cols this lane-group covers, then over
    // the 2 wc-waves via LDS.
#pragma unroll
    for (int mr = 0; mr < 4; ++mr)
#pragma unroll
        for (int rr = 0; rr < 4; ++rr) {
            float v = rowPart[mr][rr];
            v += __shfl_xor(v, 1);
            v += __shfl_xor(v, 2);
            v += __shfl_xor(v, 4);
            v += __shfl_xor(v, 8);
            if (l15 == 0)
                rowRed[wc][wr * 64 + mr * 16 + quad * 4 + rr] = v;
        }
    // Col sums: reduce over the 4 quads (rows within frag summed already),
    // then over the 2 wr-waves via LDS.
#pragma unroll
    for (int nc = 0; nc < 4; ++nc) {
        float v = colPart[nc];
        v += __shfl_xor(v, 16);
        v += __shfl_xor(v, 32);
        if (quad == 0)
            colRed[wr][wc * 64 + nc * 16 + l15] = v;
    }
    __syncthreads();

    if (tid < 128) {
        rowP[(size_t)tj * BATCH + ti * 128 + tid] =
            rowRed[0][tid] + rowRed[1][tid];
    } else if (tid < 256) {
        const int c = tid - 128;
        colP[(size_t)ti * BATCH + tj * 128 + c] =
            colRed[0][c] + colRed[1][c];
    }
}

// ---------------------------------------------------------------------------
// Kernel C: denom_k = sum of 32 tile partials (each array); loss
// contribution log(rowDenom_k) + log(colDenom_k) - 8*pos_k.
// 16 blocks x 256 thr; one atomicAdd per block into out[0] (zeroed by A).
// ---------------------------------------------------------------------------
__global__ __launch_bounds__(256) void finalize_kernel(
    const float* __restrict__ rowP, const float* __restrict__ colP,
    const float* __restrict__ pos, float* __restrict__ out)
{
    const int k = blockIdx.x * 256 + threadIdx.x;
    float rd = 0.f, cd = 0.f;
#pragma unroll
    for (int t = 0; t < NT; ++t) {
        rd += rowP[(size_t)t * BATCH + k];
        cd += colP[(size_t)t * BATCH + k];
    }
    float v = logf(rd) + logf(cd) - 8.0f * pos[k];
#pragma unroll
    for (int m = 1; m < 64; m <<= 1) v += __shfl_xor(v, m);
    __shared__ float red[4];
    if ((threadIdx.x & 63) == 0) red[threadIdx.x >> 6] = v;
    __syncthreads();
    if (threadIdx.x == 0)
        atomicAdd(out, (red[0] + red[1] + red[2] + red[3]) *
                           (1.0f / (2.0f * BATCH)));
}

extern "C" void kernel_launch(void* const* d_in, const int* in_sizes, int n_in,
                              void* d_out, int out_size, void* d_ws, size_t ws_size,
                              hipStream_t stream) {
    const float* emb_i = (const float*)d_in[0];
    const float* emb_j = (const float*)d_in[1];
    float* out = (float*)d_out;

    char* ws = (char*)d_ws;
    bf16_t* zi   = (bf16_t*)(ws);                        // 1 MB
    bf16_t* zj   = (bf16_t*)(ws + (1u << 20));           // 1 MB
    float*  rowP = (float*)(ws + (2u << 20));            // 512 KB
    float*  colP = (float*)(ws + (2u << 20) + (512u << 10)); // 512 KB
    float*  pos  = (float*)(ws + (3u << 20));            // 16 KB

    normalize_kernel<<<BATCH / 4, 256, 0, stream>>>(emb_i, emb_j, zi, zj, pos, out);
    gemm_exp_kernel<<<dim3(NT, NT), 256, 0, stream>>>(zi, zj, rowP, colP);
    finalize_kernel<<<BATCH / 256, 256, 0, stream>>>(rowP, colP, pos, out);
}

// Round 4
// 75.577 us; speedup vs baseline: 1.2495x; 1.2495x over previous
//
#include <hip/hip_runtime.h>

#define BATCH 4096
#define DIM   128
#define NT    32   // 4096 / 128 tiles per dimension
// TEMP = 0.25 -> 1/T = 4; 4*log2(e):
#define EXP_SCALE 5.770780163555854f

typedef __bf16 bf16_t;
typedef __bf16 bf16x8 __attribute__((ext_vector_type(8)));
typedef float  f32x4  __attribute__((ext_vector_type(4)));

// ---------------------------------------------------------------------------
// Kernel A: per row k, normalize emb_i[k] and emb_j[k] (fp32 math), write
// bf16 z_i, z_j to workspace, pos[k] = cos-sim in fp32. One wave per row.
// Blocks 0..7 zero exactly the rowDenom/colDenom region (8 blocks x 256 thr
// x 4 floats = 8192 floats = 32 KB). NOTE: the previous session's version
// used 16 blocks, overshooting into pos[] -- a cross-block race with the
// pos[k] writes. 8 blocks covers denoms exactly; race-free, same cost.
// ---------------------------------------------------------------------------
__global__ __launch_bounds__(256) void normalize_kernel(
    const float* __restrict__ emb_i, const float* __restrict__ emb_j,
    bf16_t* __restrict__ zi, bf16_t* __restrict__ zj, float* __restrict__ pos,
    float* __restrict__ denoms /* rowDenom(4096) ++ colDenom(4096) */)
{
    if (blockIdx.x < 8) {
        int idx = (blockIdx.x * 256 + threadIdx.x) * 4;
        *(float4*)&denoms[idx] = make_float4(0.f, 0.f, 0.f, 0.f);
    }

    int wave = threadIdx.x >> 6;
    int lane = threadIdx.x & 63;
    int k = blockIdx.x * 4 + wave;

    const float2* ei = (const float2*)(emb_i + (size_t)k * DIM);
    const float2* ej = (const float2*)(emb_j + (size_t)k * DIM);
    float2 a = ei[lane];
    float2 b = ej[lane];

    float sii = a.x * a.x + a.y * a.y;
    float sjj = b.x * b.x + b.y * b.y;
    float sij = a.x * b.x + a.y * b.y;
#pragma unroll
    for (int m = 1; m < 64; m <<= 1) {
        sii += __shfl_xor(sii, m);
        sjj += __shfl_xor(sjj, m);
        sij += __shfl_xor(sij, m);
    }
    float inv_i = 1.0f / fmaxf(sqrtf(sii), 1e-12f);
    float inv_j = 1.0f / fmaxf(sqrtf(sjj), 1e-12f);

    struct bf16_2 { bf16_t x, y; };
    bf16_2 pi, pj;
    pi.x = (bf16_t)(a.x * inv_i);  pi.y = (bf16_t)(a.y * inv_i);
    pj.x = (bf16_t)(b.x * inv_j);  pj.y = (bf16_t)(b.y * inv_j);
    ((bf16_2*)(zi + (size_t)k * DIM))[lane] = pi;
    ((bf16_2*)(zj + (size_t)k * DIM))[lane] = pj;

    if (lane == 0) pos[k] = sij * inv_i * inv_j;
}

// ---------------------------------------------------------------------------
// Kernel B: 128x128 tile of S = Zi * Zj^T per block. Identical to the
// 74.6 us baseline kernel EXCEPT: 1-D grid of 1024 with an XCD-chunk
// swizzle (T1). Default round-robin block->XCD placement puts consecutive
// blocks (which share a zj panel) on different XCDs -> zero L2 reuse,
// ~128 MB of cross-XCD staging traffic. Chunked mapping gives each XCD
// 128 contiguous blocks = 4 tj-rows x all 32 ti: per-XCD first-touch
// ~1.1 MB, rest XCD-L2 hits. 1024 % 8 == 0 -> bijective.
// bf16 MFMA 16x16x32, K=128 in 4 steps. Epilogue: e = exp2(EXP_SCALE*s);
// row partials complete within a wave (16-lane shfl) -> 1 atomic per row;
// col partials cross-wave LDS reduce -> 128 coalesced atomics per block.
// LDS rows padded 128->136 (row stride 272 B -> only free 2-way
// conflicts; 16B alignment preserved for b128 access).
// ---------------------------------------------------------------------------
__global__ __launch_bounds__(256) void gemm_exp_kernel(
    const bf16_t* __restrict__ zi, const bf16_t* __restrict__ zj,
    float* __restrict__ rowDenom, float* __restrict__ colDenom)
{
    __shared__ __align__(16) bf16_t zi_s[128][136];
    __shared__ __align__(16) bf16_t zj_s[128][136];
    __shared__ float colRed[4][128];

    const int tid = threadIdx.x;

    // XCD-chunk swizzle: orig dispatch order round-robins XCDs; remap so
    // each XCD owns a contiguous chunk of the (ti, tj) grid.
    const int orig = blockIdx.x;
    const int swz  = ((orig & 7) << 7) | (orig >> 3);
    const int ti = swz & 31;          // x-fastest within chunk
    const int tj = swz >> 5;

    // Stage 128x128 bf16 of each matrix: 2048 16B-chunks / matrix, 8 iters.
#pragma unroll
    for (int it = 0; it < 8; ++it) {
        int c = it * 256 + tid;
        int row = c >> 4;          // 16 chunks per row
        int col = (c & 15) << 3;   // 8 bf16 per chunk
        *(uint4*)&zi_s[row][col] =
            *(const uint4*)(zi + ((size_t)(ti * 128 + row)) * DIM + col);
        *(uint4*)&zj_s[row][col] =
            *(const uint4*)(zj + ((size_t)(tj * 128 + row)) * DIM + col);
    }
    __syncthreads();

    const int wave = tid >> 6;
    const int lane = tid & 63;
    const int l15  = lane & 15;
    const int quad = lane >> 4;

    const f32x4 vzero = {0.f, 0.f, 0.f, 0.f};
    f32x4 acc[2][8];
#pragma unroll
    for (int rt = 0; rt < 2; ++rt)
#pragma unroll
        for (int ct = 0; ct < 8; ++ct) acc[rt][ct] = vzero;

#pragma unroll
    for (int ks = 0; ks < 4; ++ks) {
        int k0 = ks * 32 + quad * 8;
        bf16x8 afrag[2], bfrag[8];
#pragma unroll
        for (int rt = 0; rt < 2; ++rt)
            afrag[rt] = *(const bf16x8*)&zi_s[(wave * 2 + rt) * 16 + l15][k0];
#pragma unroll
        for (int ct = 0; ct < 8; ++ct)
            bfrag[ct] = *(const bf16x8*)&zj_s[ct * 16 + l15][k0];
#pragma unroll
        for (int rt = 0; rt < 2; ++rt)
#pragma unroll
            for (int ct = 0; ct < 8; ++ct)
                acc[rt][ct] = __builtin_amdgcn_mfma_f32_16x16x32_bf16(
                    afrag[rt], bfrag[ct], acc[rt][ct], 0, 0, 0);
    }

    // Epilogue: exp and partial sums.
    float rowPart[2][4] = {{0.f, 0.f, 0.f, 0.f}, {0.f, 0.f, 0.f, 0.f}};
    float colPart[8]    = {0.f, 0.f, 0.f, 0.f, 0.f, 0.f, 0.f, 0.f};
#pragma unroll
    for (int rt = 0; rt < 2; ++rt)
#pragma unroll
        for (int ct = 0; ct < 8; ++ct)
#pragma unroll
            for (int r = 0; r < 4; ++r) {
                float e = exp2f(acc[rt][ct][r] * EXP_SCALE);
                rowPart[rt][r] += e;   // row = (wave*2+rt)*16 + quad*4 + r
                colPart[ct]    += e;   // col = ct*16 + l15
            }

    // Row sums: each wave's rows see all 128 tile columns; 16-lane shfl
    // reduce completes them. One atomic per row per block.
#pragma unroll
    for (int rt = 0; rt < 2; ++rt)
#pragma unroll
        for (int r = 0; r < 4; ++r) {
            float v = rowPart[rt][r];
            v += __shfl_xor(v, 1);
            v += __shfl_xor(v, 2);
            v += __shfl_xor(v, 4);
            v += __shfl_xor(v, 8);
            if (l15 == 0) {
                int grow = ti * 128 + (wave * 2 + rt) * 16 + quad * 4 + r;
                atomicAdd(&rowDenom[grow], v);
            }
        }

    // Col sums: quad shfl-reduce, then cross-wave LDS reduce, then one
    // coalesced atomic per column per block.
#pragma unroll
    for (int ct = 0; ct < 8; ++ct) {
        float v = colPart[ct];
        v += __shfl_xor(v, 16);
        v += __shfl_xor(v, 32);
        if (quad == 0) colRed[wave][ct * 16 + l15] = v;
    }
    __syncthreads();
    if (tid < 128) {
        float s = colRed[0][tid] + colRed[1][tid] + colRed[2][tid] + colRed[3][tid];
        atomicAdd(&colDenom[tj * 128 + tid], s);
    }
}

// ---------------------------------------------------------------------------
// Kernel C: loss = (1/2B) * sum_k [log rowDenom_k + log colDenom_k - 8*pos_k]
// Only 48 KB of reads -> single block is fine.
// ---------------------------------------------------------------------------
__global__ __launch_bounds__(256) void finalize_kernel(
    const float* __restrict__ denoms, const float* __restrict__ pos,
    float* __restrict__ out)
{
    const float* rowDenom = denoms;
    const float* colDenom = denoms + BATCH;
    int tid = threadIdx.x;
    float acc = 0.f;
#pragma unroll
    for (int it = 0; it < 16; ++it) {
        int k = it * 256 + tid;
        acc += logf(rowDenom[k]) + logf(colDenom[k]) - 8.0f * pos[k];
    }
#pragma unroll
    for (int m = 1; m < 64; m <<= 1) acc += __shfl_xor(acc, m);
    __shared__ float red[4];
    if ((tid & 63) == 0) red[tid >> 6] = acc;
    __syncthreads();
    if (tid == 0)
        out[0] = (red[0] + red[1] + red[2] + red[3]) * (1.0f / (2.0f * BATCH));
}

extern "C" void kernel_launch(void* const* d_in, const int* in_sizes, int n_in,
                              void* d_out, int out_size, void* d_ws, size_t ws_size,
                              hipStream_t stream) {
    const float* emb_i = (const float*)d_in[0];
    const float* emb_j = (const float*)d_in[1];
    float* out = (float*)d_out;

    char* ws = (char*)d_ws;
    bf16_t* zi     = (bf16_t*)(ws);                 // 1 MB
    bf16_t* zj     = (bf16_t*)(ws + (1u << 20));    // 1 MB
    float*  denoms = (float*)(ws + (2u << 20));     // 32 KB (row ++ col)
    float*  pos    = denoms + 2 * BATCH;            // 16 KB

    normalize_kernel<<<BATCH / 4, 256, 0, stream>>>(emb_i, emb_j, zi, zj, pos, denoms);
    gemm_exp_kernel<<<1024, 256, 0, stream>>>(zi, zj, denoms, denoms + BATCH);
    finalize_kernel<<<1, 256, 0, stream>>>(denoms, pos, out);
}